// Round 9
// baseline (37.842 us; speedup 1.0000x reference)
//
#include <hip/hip_runtime.h>

// Problem constants: B=8, S=4096, D=1024, A=3, C=2, K=64, MARGIN=5
#define DIM      1024
#define SA       12288      // S*A per batch
#define KSAMP    64
#define PRED_OFF 1          // d_out layout: [loss(1) | predict(98304) | total_idx(1536) | cand(512)]
#define TI_OFF   (1 + 98304)
#define CAND_OFF (1 + 98304 + 1536)
#define SCAN_BLOCKS 8
#define GEMM_BLOCKS 2048

typedef float f32x4 __attribute__((ext_vector_type(4)));

// ---------------- K1: 8 scan blocks + 2048 diff-form GEMM blocks ----------------
// ROUND-9 CHANGE: explicit depth-4 prefetch ring for the X loads (fully unrolled,
// compile-time slot indices). Round-7 showed the loop's rate is set by loads kept
// in flight by the SCHEDULE (f32's short tails collapsed it); this pins 4
// outstanding loads per thread regardless of FMA scheduling. Arithmetic is
// bit-identical to round 6 (f64 accum, same chain order, same butterfly).
// Round ledger: occupancy x2 null (r5); f32 -10us (r7); nt-loads -3us (r8).
__global__ __launch_bounds__(256, 8)
void k_gemm_scan(const float* __restrict__ X, const float* __restrict__ W,
                 const float* __restrict__ bias, const int* __restrict__ labels,
                 float* __restrict__ outPred, float* __restrict__ ldiff,
                 int* __restrict__ wsPos, float* __restrict__ outTI) {
  const int tid = threadIdx.x;

  if (blockIdx.x < SCAN_BLOCKS) {
    // ---------- scan path: batch b ----------
    // top_k == first 64 positives in flat order (forced 2.0 > any sigmoid,
    // ~6144 positives >> 64). 256 labels loaded in parallel, 4 wave-ballots ->
    // LDS, rank = mask prefix; ~1e-16 serial fallback below.
    const int b = blockIdx.x;
    __shared__ unsigned long long s_mask[4];
    const int wave = tid >> 6;
    const int lane = tid & 63;
    const int lab = labels[b * SA + tid];
    const unsigned long long m = __ballot(lab == 1);
    if (lane == 0) s_mask[wave] = m;
    __syncthreads();
    int before = 0;
#pragma unroll
    for (int w2 = 0; w2 < 4; ++w2)
      if (w2 < wave) before += __popcll(s_mask[w2]);
    if (lab == 1) {
      const int rank = before + __popcll(m & ((1ull << lane) - 1ull));
      if (rank < KSAMP) {
        wsPos[b * KSAMP + rank] = tid;
        const int seq = tid / 3, anc = tid - seq * 3;
        const int gk = b * KSAMP + rank;
        outTI[gk * 3 + 0] = (float)b;
        outTI[gk * 3 + 1] = (float)seq;
        outTI[gk * 3 + 2] = (float)anc;
      }
    }
    int totAll = 0;
#pragma unroll
    for (int w2 = 0; w2 < 4; ++w2) totAll += __popcll(s_mask[w2]);
    if (totAll < KSAMP && wave == 0) {             // deterministic fallback (never in practice)
      int found = totAll;
      for (int base = 256; base < SA && found < KSAMP; base += 64) {
        const int lab2 = labels[b * SA + base + lane];
        const unsigned long long m2 = __ballot(lab2 == 1);
        if (lab2 == 1) {
          const int rank = found + __popcll(m2 & ((1ull << lane) - 1ull));
          if (rank < KSAMP) {
            const int pos = base + lane;
            wsPos[b * KSAMP + rank] = pos;
            const int seq = pos / 3, anc = pos - seq * 3;
            const int gk = b * KSAMP + rank;
            outTI[gk * 3 + 0] = (float)b;
            outTI[gk * 3 + 1] = (float)seq;
            outTI[gk * 3 + 2] = (float)anc;
          }
        }
        found += __popcll(m2);
      }
    }
    return;
  }

  // ---------- GEMM path: ldiff[row][a] = dot(X[row], W[:,2a+1]-W[:,2a]) + bd[a] ----------
  __shared__ float lds_wd[3 * 1024];
  for (int d = tid; d < 1024; d += 256) {
    const float2 w01 = *reinterpret_cast<const float2*>(W + d * 6);
    const float2 w23 = *reinterpret_cast<const float2*>(W + d * 6 + 2);
    const float2 w45 = *reinterpret_cast<const float2*>(W + d * 6 + 4);
    lds_wd[0 * 1024 + d] = w01.y - w01.x;
    lds_wd[1 * 1024 + d] = w23.y - w23.x;
    lds_wd[2 * 1024 + d] = w45.y - w45.x;
  }
  __syncthreads();

  const int wave = tid >> 6;
  const int lane = tid & 63;
  const int q    = lane & 15;
  const int p    = lane >> 4;
  const int row  = (blockIdx.x - SCAN_BLOCKS) * 16 + wave * 4 + p;
  const float* xr = X + (size_t)row * DIM;
  const int qb = q * 4;

  double acc0 = 0.0, acc1 = 0.0, acc2 = 0.0;

  // depth-4 prefetch ring; all slot indices compile-time (full unroll)
  f32x4 xs[4];
#pragma unroll
  for (int j0 = 0; j0 < 4; ++j0)
    xs[j0] = *reinterpret_cast<const f32x4*>(xr + j0 * 64 + qb);

#pragma unroll
  for (int j = 0; j < 16; ++j) {
    const f32x4 x4 = xs[j & 3];
    if (j + 4 < 16)
      xs[j & 3] = *reinterpret_cast<const f32x4*>(xr + (j + 4) * 64 + qb);
    const int d = j * 64 + qb;
    const float4 w0 = *reinterpret_cast<const float4*>(&lds_wd[d]);
    const float4 w1 = *reinterpret_cast<const float4*>(&lds_wd[1024 + d]);
    const float4 w2 = *reinterpret_cast<const float4*>(&lds_wd[2048 + d]);
    const double x0 = x4[0], x1 = x4[1], x2 = x4[2], x3 = x4[3];
    acc0 += x0 * (double)w0.x + x1 * (double)w0.y + x2 * (double)w0.z + x3 * (double)w0.w;
    acc1 += x0 * (double)w1.x + x1 * (double)w1.y + x2 * (double)w1.z + x3 * (double)w1.w;
    acc2 += x0 * (double)w2.x + x1 * (double)w2.y + x2 * (double)w2.z + x3 * (double)w2.w;
  }

  // butterfly across the 16 q-lanes (bits 0..3); p-groups independent
#pragma unroll
  for (int s = 1; s < 16; s <<= 1) {
    acc0 += __shfl_xor(acc0, s, 64);
    acc1 += __shfl_xor(acc1, s, 64);
    acc2 += __shfl_xor(acc2, s, 64);
  }

  const double bd0 = (double)bias[1] - (double)bias[0];
  const double bd1 = (double)bias[3] - (double)bias[2];
  const double bd2 = (double)bias[5] - (double)bias[4];
  const float f0 = (float)(acc0 + bd0);
  const float f1 = (float)(acc1 + bd1);
  const float f2 = (float)(acc2 + bd2);

  if (q == 0) {
    ldiff[(size_t)row * 3 + 0] = f0;
    ldiff[(size_t)row * 3 + 1] = f1;
    ldiff[(size_t)row * 3 + 2] = f2;
  } else if (q == 4) {
    outPred[(size_t)row * 3 + 0] = (f0 > 0.0f) ? 1.0f : 0.0f;
    outPred[(size_t)row * 3 + 1] = (f1 > 0.0f) ? 1.0f : 0.0f;
    outPred[(size_t)row * 3 + 2] = (f2 > 0.0f) ? 1.0f : 0.0f;
  }
}

// ---------------- K2: tiny finalize — gather ldiff, cand, loss ----------------
__global__ __launch_bounds__(512)
void k_final(const float* __restrict__ ldiff, const int* __restrict__ wsPos,
             float* __restrict__ outCand, float* __restrict__ out0) {
  __shared__ float s_part[8];
  const int tid  = threadIdx.x;
  const int w    = tid >> 6;       // batch
  const int lane = tid & 63;

  const int pos = wsPos[w * KSAMP + lane];
  const float ld = ldiff[w * SA + pos];
  const float term = fmaxf(0.0f, 5.0f - ld);   // sampled label is 1 by construction
  outCand[w * KSAMP + lane] = (ld > 0.0f) ? 1.0f : 0.0f;

  float t = term;
#pragma unroll
  for (int s = 1; s < 64; s <<= 1) t += __shfl_xor(t, s, 64);
  if (lane == 0) s_part[w] = t;
  __syncthreads();
  if (tid == 0) {
    float tot = 0.0f;
#pragma unroll
    for (int i = 0; i < 8; ++i) tot += s_part[i];
    out0[0] = tot * (1.0f / 1024.0f);   // /512 samples /C=2
  }
}

extern "C" void kernel_launch(void* const* d_in, const int* in_sizes, int n_in,
                              void* d_out, int out_size, void* d_ws, size_t ws_size,
                              hipStream_t stream) {
  const float* X     = (const float*)d_in[0];
  const float* W     = (const float*)d_in[1];
  const float* bias  = (const float*)d_in[2];
  const int*   lab   = (const int*)d_in[3];
  float* out   = (float*)d_out;
  float* ldiff = (float*)d_ws;                                // 98304 f32 = 384 KB
  int*   wsPos = (int*)((char*)d_ws + 98304 * sizeof(float)); // 512 ints

  k_gemm_scan<<<GEMM_BLOCKS + SCAN_BLOCKS, 256, 0, stream>>>(
      X, W, bias, lab, out + PRED_OFF, ldiff, wsPos, out + TI_OFF);
  k_final<<<1, 512, 0, stream>>>(ldiff, wsPos, out + CAND_OFF, out);
}

// Round 10
// 30.188 us; speedup vs baseline: 1.2535x; 1.2535x over previous
//
#include <hip/hip_runtime.h>

// Problem constants: B=8, S=4096, D=1024, A=3, C=2, K=64, MARGIN=5
#define DIM      1024
#define SA       12288      // S*A per batch
#define KSAMP    64
#define PRED_OFF 1          // d_out layout: [loss(1) | predict(98304) | total_idx(1536) | cand(512)]
#define TI_OFF   (1 + 98304)
#define CAND_OFF (1 + 98304 + 1536)
#define GEMM_BLOCKS 2048

// ---------------- K1: 2048 blocks == exact residency capacity ----------------
// ROUND-10 CHANGE: grid is EXACTLY 2048 blocks (= 8 blocks/CU x 256 CU capacity at
// __launch_bounds__(256,8)). Round 6's 2056-block grid over-subscribed by 8: the
// last 8 GEMM blocks waited ~3us for the scan blocks to retire, then ran their full
// GEMM serially after everyone else — a pure tail. The batch-b scan now folds into
// GEMM block b*256 (8 of the 2048): label loads issue first (latency hides under
// W-staging), ballot/rank after the single __syncthreads, then normal GEMM share.
// GEMM arithmetic is byte-identical to round 6 (f64 accum — r7 proved f32 regresses;
// plain loads — r8 proved nt regresses; compiler schedule — r9 proved rings regress).
__global__ __launch_bounds__(256, 8)
void k_gemm_scan(const float* __restrict__ X, const float* __restrict__ W,
                 const float* __restrict__ bias, const int* __restrict__ labels,
                 float* __restrict__ outPred, float* __restrict__ ldiff,
                 int* __restrict__ wsPos, float* __restrict__ outTI) {
  const int tid = threadIdx.x;
  const int wave = tid >> 6;
  const int lane = tid & 63;
  const bool isScan = ((blockIdx.x & 255) == 0) && ((blockIdx.x >> 8) < 8);
  const int b = blockIdx.x >> 8;     // batch, valid when isScan

  __shared__ float lds_wd[3 * 1024];
  __shared__ unsigned long long s_mask[4];

  // scan label load issues FIRST so its latency hides under the W staging
  int lab = 0;
  if (isScan) lab = labels[b * SA + tid];

  for (int d = tid; d < 1024; d += 256) {
    const float2 w01 = *reinterpret_cast<const float2*>(W + d * 6);
    const float2 w23 = *reinterpret_cast<const float2*>(W + d * 6 + 2);
    const float2 w45 = *reinterpret_cast<const float2*>(W + d * 6 + 4);
    lds_wd[0 * 1024 + d] = w01.y - w01.x;
    lds_wd[1 * 1024 + d] = w23.y - w23.x;
    lds_wd[2 * 1024 + d] = w45.y - w45.x;
  }
  if (isScan) {
    const unsigned long long m = __ballot(lab == 1);
    if (lane == 0) s_mask[wave] = m;
  }
  __syncthreads();   // covers lds_wd staging AND s_mask

  if (isScan) {
    // top_k == first 64 positives in flat order (forced 2.0 > any sigmoid,
    // ~6144 positives >> 64). Rank = LDS mask prefix; ~1e-16 serial fallback.
    const unsigned long long m = s_mask[wave];
    int before = 0;
#pragma unroll
    for (int w2 = 0; w2 < 4; ++w2)
      if (w2 < wave) before += __popcll(s_mask[w2]);
    if (lab == 1) {
      const int rank = before + __popcll(m & ((1ull << lane) - 1ull));
      if (rank < KSAMP) {
        wsPos[b * KSAMP + rank] = tid;
        const int seq = tid / 3, anc = tid - seq * 3;
        const int gk = b * KSAMP + rank;
        outTI[gk * 3 + 0] = (float)b;
        outTI[gk * 3 + 1] = (float)seq;
        outTI[gk * 3 + 2] = (float)anc;
      }
    }
    int totAll = 0;
#pragma unroll
    for (int w2 = 0; w2 < 4; ++w2) totAll += __popcll(s_mask[w2]);
    if (totAll < KSAMP && wave == 0) {             // deterministic fallback (never in practice)
      int found = totAll;
      for (int base = 256; base < SA && found < KSAMP; base += 64) {
        const int lab2 = labels[b * SA + base + lane];
        const unsigned long long m2 = __ballot(lab2 == 1);
        if (lab2 == 1) {
          const int rank = found + __popcll(m2 & ((1ull << lane) - 1ull));
          if (rank < KSAMP) {
            const int pos = base + lane;
            wsPos[b * KSAMP + rank] = pos;
            const int seq = pos / 3, anc = pos - seq * 3;
            const int gk = b * KSAMP + rank;
            outTI[gk * 3 + 0] = (float)b;
            outTI[gk * 3 + 1] = (float)seq;
            outTI[gk * 3 + 2] = (float)anc;
          }
        }
        found += __popcll(m2);
      }
    }
  }

  // ---------- GEMM path (ALL 2048 blocks): ldiff[row][a] = X[row]·(W[:,2a+1]-W[:,2a]) + bd[a] ----------
  const int q    = lane & 15;
  const int p    = lane >> 4;
  const int row  = blockIdx.x * 16 + wave * 4 + p;
  const float* xr = X + (size_t)row * DIM;
  const int qb = q * 4;

  double acc0 = 0.0, acc1 = 0.0, acc2 = 0.0;

#pragma unroll 4
  for (int j = 0; j < 16; ++j) {
    const int d = j * 64 + qb;
    const float4 x4 = *reinterpret_cast<const float4*>(xr + d);
    const float4 w0 = *reinterpret_cast<const float4*>(&lds_wd[d]);
    const float4 w1 = *reinterpret_cast<const float4*>(&lds_wd[1024 + d]);
    const float4 w2 = *reinterpret_cast<const float4*>(&lds_wd[2048 + d]);
    const double x0 = x4.x, x1 = x4.y, x2 = x4.z, x3 = x4.w;
    acc0 += x0 * (double)w0.x + x1 * (double)w0.y + x2 * (double)w0.z + x3 * (double)w0.w;
    acc1 += x0 * (double)w1.x + x1 * (double)w1.y + x2 * (double)w1.z + x3 * (double)w1.w;
    acc2 += x0 * (double)w2.x + x1 * (double)w2.y + x2 * (double)w2.z + x3 * (double)w2.w;
  }

  // butterfly across the 16 q-lanes (bits 0..3); p-groups independent
#pragma unroll
  for (int s = 1; s < 16; s <<= 1) {
    acc0 += __shfl_xor(acc0, s, 64);
    acc1 += __shfl_xor(acc1, s, 64);
    acc2 += __shfl_xor(acc2, s, 64);
  }

  const double bd0 = (double)bias[1] - (double)bias[0];
  const double bd1 = (double)bias[3] - (double)bias[2];
  const double bd2 = (double)bias[5] - (double)bias[4];
  const float f0 = (float)(acc0 + bd0);
  const float f1 = (float)(acc1 + bd1);
  const float f2 = (float)(acc2 + bd2);

  if (q == 0) {
    ldiff[(size_t)row * 3 + 0] = f0;
    ldiff[(size_t)row * 3 + 1] = f1;
    ldiff[(size_t)row * 3 + 2] = f2;
  } else if (q == 4) {
    outPred[(size_t)row * 3 + 0] = (f0 > 0.0f) ? 1.0f : 0.0f;
    outPred[(size_t)row * 3 + 1] = (f1 > 0.0f) ? 1.0f : 0.0f;
    outPred[(size_t)row * 3 + 2] = (f2 > 0.0f) ? 1.0f : 0.0f;
  }
}

// ---------------- K2: tiny finalize — gather ldiff, cand, loss ----------------
__global__ __launch_bounds__(512)
void k_final(const float* __restrict__ ldiff, const int* __restrict__ wsPos,
             float* __restrict__ outCand, float* __restrict__ out0) {
  __shared__ float s_part[8];
  const int tid  = threadIdx.x;
  const int w    = tid >> 6;       // batch
  const int lane = tid & 63;

  const int pos = wsPos[w * KSAMP + lane];
  const float ld = ldiff[w * SA + pos];
  const float term = fmaxf(0.0f, 5.0f - ld);   // sampled label is 1 by construction
  outCand[w * KSAMP + lane] = (ld > 0.0f) ? 1.0f : 0.0f;

  float t = term;
#pragma unroll
  for (int s = 1; s < 64; s <<= 1) t += __shfl_xor(t, s, 64);
  if (lane == 0) s_part[w] = t;
  __syncthreads();
  if (tid == 0) {
    float tot = 0.0f;
#pragma unroll
    for (int i = 0; i < 8; ++i) tot += s_part[i];
    out0[0] = tot * (1.0f / 1024.0f);   // /512 samples /C=2
  }
}

extern "C" void kernel_launch(void* const* d_in, const int* in_sizes, int n_in,
                              void* d_out, int out_size, void* d_ws, size_t ws_size,
                              hipStream_t stream) {
  const float* X     = (const float*)d_in[0];
  const float* W     = (const float*)d_in[1];
  const float* bias  = (const float*)d_in[2];
  const int*   lab   = (const int*)d_in[3];
  float* out   = (float*)d_out;
  float* ldiff = (float*)d_ws;                                // 98304 f32 = 384 KB
  int*   wsPos = (int*)((char*)d_ws + 98304 * sizeof(float)); // 512 ints

  k_gemm_scan<<<GEMM_BLOCKS, 256, 0, stream>>>(
      X, W, bias, lab, out + PRED_OFF, ldiff, wsPos, out + TI_OFF);
  k_final<<<1, 512, 0, stream>>>(ldiff, wsPos, out + CAND_OFF, out);
}